// Round 15
// baseline (228.604 us; speedup 1.0000x reference)
//
#include <hip/hip_runtime.h>
#include <hip/hip_bf16.h>
#include <stdint.h>

#define B_  4
#define S_  2048
#define BS_ (B_ * S_)   // 8192 tokens
#define D_  1024
#define O_  1024
#define H_  8

#define BM 128
#define BN 128
#define BK 64
#define NT 128          // K' tiles: (h,k) combined, 8*1024/64

typedef unsigned short u16;
typedef __attribute__((ext_vector_type(8))) short     short8;
typedef __attribute__((ext_vector_type(8))) unsigned short ushort8v;
typedef __attribute__((ext_vector_type(4))) float     f32x4;

__device__ __forceinline__ u16 f2bf(float f) {
  unsigned u = __float_as_uint(f);
  unsigned r = (u + 0x7fffu + ((u >> 16) & 1u)) >> 16;
  return (u16)r;
}

#define GLOAD16(gp, lp)                                                        \
  __builtin_amdgcn_global_load_lds(                                            \
      (const __attribute__((address_space(1))) void*)(gp),                     \
      (__attribute__((address_space(3))) void*)(lp), 16, 0, 0)

// ---------------------------------------------------------------------------
// Kernel 1: gates (f32, one wave per token) + x -> bf16 conversion
// ---------------------------------------------------------------------------
__global__ __launch_bounds__(256) void gate_conv_kernel(
    const float* __restrict__ x, const float* __restrict__ gate_w,
    const float* __restrict__ gate_b, u16* __restrict__ x_bf,
    float* __restrict__ g_out) {
  const int wave  = threadIdx.x >> 6;
  const int lane  = threadIdx.x & 63;
  const int token = blockIdx.x * 4 + wave;
  const float* xr = x + (size_t)token * D_;
  const int d0 = lane * 16;

  float4 xv[4];
#pragma unroll
  for (int i = 0; i < 4; ++i) xv[i] = *(const float4*)(xr + d0 + i * 4);

  ushort8v lo, hi;
#pragma unroll
  for (int i = 0; i < 2; ++i) {
    lo[i * 4 + 0] = f2bf(xv[i].x); lo[i * 4 + 1] = f2bf(xv[i].y);
    lo[i * 4 + 2] = f2bf(xv[i].z); lo[i * 4 + 3] = f2bf(xv[i].w);
    hi[i * 4 + 0] = f2bf(xv[2 + i].x); hi[i * 4 + 1] = f2bf(xv[2 + i].y);
    hi[i * 4 + 2] = f2bf(xv[2 + i].z); hi[i * 4 + 3] = f2bf(xv[2 + i].w);
  }
  *(ushort8v*)(x_bf + (size_t)token * D_ + d0) = lo;
  *(ushort8v*)(x_bf + (size_t)token * D_ + d0 + 8) = hi;

  float s[H_];
#pragma unroll
  for (int h = 0; h < H_; ++h) {
    const float* gw = gate_w + h * D_ + d0;
    float a = 0.f;
#pragma unroll
    for (int i = 0; i < 4; ++i) {
      float4 w = *(const float4*)(gw + i * 4);
      a += xv[i].x * w.x + xv[i].y * w.y + xv[i].z * w.z + xv[i].w * w.w;
    }
    s[h] = a;
  }
#pragma unroll
  for (int h = 0; h < H_; ++h) {
#pragma unroll
    for (int off = 32; off > 0; off >>= 1) s[h] += __shfl_xor(s[h], off);
    s[h] += gate_b[h];
  }
  float m = s[0];
#pragma unroll
  for (int h = 1; h < H_; ++h) m = fmaxf(m, s[h]);
  float sum = 0.f;
#pragma unroll
  for (int h = 0; h < H_; ++h) { s[h] = expf(s[h] - m); sum += s[h]; }
  const float inv = 1.0f / sum;
#pragma unroll
  for (int h = 0; h < H_; ++h) s[h] *= inv;

  if (lane == 0) {
    float4 g0 = make_float4(s[0], s[1], s[2], s[3]);
    float4 g1 = make_float4(s[4], s[5], s[6], s[7]);
    *(float4*)(g_out + (size_t)token * H_)     = g0;
    *(float4*)(g_out + (size_t)token * H_ + 4) = g1;
  }
}

// ---------------------------------------------------------------------------
// Kernel 2: expert_w f32 -> bf16
// ---------------------------------------------------------------------------
__global__ __launch_bounds__(256) void convw_kernel(
    const float* __restrict__ w, u16* __restrict__ wb) {
  size_t i = ((size_t)blockIdx.x * 256 + threadIdx.x) * 8;
  float4 a = *(const float4*)(w + i);
  float4 b = *(const float4*)(w + i + 4);
  ushort8v v;
  v[0] = f2bf(a.x); v[1] = f2bf(a.y); v[2] = f2bf(a.z); v[3] = f2bf(a.w);
  v[4] = f2bf(b.x); v[5] = f2bf(b.y); v[6] = f2bf(b.z); v[7] = f2bf(b.w);
  *(ushort8v*)(wb + i) = v;
}

// ---------------------------------------------------------------------------
// Kernel 3: fused MoE GEMM == R14 structure with the STAGE_A call fixed.
// R14 BUG: STAGE_A's macro multiplies its arg by BK (expects k-tile INDEX);
// the in-loop call passed (t1&15)*64 (element offset) -> A offset k*4096
// elems (4 rows down) -> garbage A tiles -> absmax 2.07.  Fix: pass t1&15.
// Structure (hypothesis under test, from R13 post-mortem): R13 ran 1
// block/CU (156 KB LDS), all 8 waves in one barrier-lockstep, LDS pipe
// ~74% busy, MfmaUtil 43.  Halve the block: BM 128, 4 waves (2Mx2N,
// per-wave 64x64 unchanged), 2-deep ring, LDS 72 KB -> 2 blocks/CU so one
// block's MFMA covers the other's read-ramp + barrier (m114 overlap).
// Tile body: {16 ds_read_b128, 8 gload_lds (stage t+1), setprio(1),
// 32 MFMA, setprio(0), vmcnt(0), s_barrier, fold at h-boundary}.
// Verified components: 3-bit XOR swizzle (0 conflicts), XCD row-panel map
// (FETCH 99MB), per-h fold acc += g_h*(part+eb), C/D layout.
// ---------------------------------------------------------------------------
__global__ __launch_bounds__(256) void moe_gemm_kernel(
    const u16* __restrict__ Xb, const u16* __restrict__ Wb,
    const float* __restrict__ g, const float* __restrict__ eb,
    float* __restrict__ out) {
  __shared__ __align__(16) u16 As[2][BM * BK];   // 2 x 16 KB
  __shared__ __align__(16) u16 Bs[2][BN * BK];   // 2 x 16 KB
  __shared__ float gs[H_][BM];                   // 4 KB, transposed
  __shared__ float ebs[H_][BN];                  // 4 KB

  const int tid  = threadIdx.x;
  const int wave = tid >> 6;
  const int lane = tid & 63;

  // ---- XCD-affine mapping: xcd = bx&7 owns row panels 8*xcd + (bx>>6) ----
  const int bx   = blockIdx.x;                 // 512 blocks
  const int row0 = ((bx & 7) * 8 + (bx >> 6)) * BM;   // 64 row panels
  const int col0 = ((bx >> 3) & 7) * BN;               // 8 col panels

  if (tid < BM) {
    const float* gr = g + (size_t)(row0 + tid) * H_;
#pragma unroll
    for (int h = 0; h < H_; ++h) gs[h][tid] = gr[h];
  }
  for (int i = tid; i < H_ * BN; i += 256) {
    int h = i >> 7, c = i & 127;
    ebs[h][c] = eb[h * O_ + col0 + c];
  }

  const int wm = wave >> 1;  // 0..1 : 64-row band
  const int wn = wave & 1;   // 0..1 : 64-col band

  // ---- staging source (inverse-swizzled global addr; LDS dest linear) ----
  // involution: elem_col ^= (row&7)<<3 ; staged row&7 == (lane>>3)&7
  const int s_row = wave * 8 + (lane >> 3);               // rows 0..31
  const int s_col = ((lane & 7) * 8) ^ (((lane >> 3) & 7) << 3);
  const u16* a_base = Xb + (size_t)(row0 + s_row) * D_ + s_col;
  const u16* b_base = Wb + (size_t)(col0 + s_row) * D_ + s_col;
  const int lds_off = (wave * 8) * BK;                    // elems, wave-uniform

// kk_ is the k-tile INDEX (elements offset = kk_ * BK)
#define STAGE_A(kk_, buf_)                                                     \
  {                                                                            \
    const u16* ap = a_base + (size_t)(kk_) * BK;                               \
    GLOAD16(ap,                     &As[buf_][lds_off]);                       \
    GLOAD16(ap + (size_t)32  * D_,  &As[buf_][lds_off + 32 * BK]);             \
    GLOAD16(ap + (size_t)64  * D_,  &As[buf_][lds_off + 64 * BK]);             \
    GLOAD16(ap + (size_t)96  * D_,  &As[buf_][lds_off + 96 * BK]);             \
  }
// off_ is a raw ELEMENT offset from b_base
#define STAGE_B(off_, buf_)                                                    \
  {                                                                            \
    const u16* bp = b_base + (off_);                                           \
    GLOAD16(bp,                     &Bs[buf_][lds_off]);                       \
    GLOAD16(bp + (size_t)32  * D_,  &Bs[buf_][lds_off + 32 * BK]);             \
    GLOAD16(bp + (size_t)64  * D_,  &Bs[buf_][lds_off + 64 * BK]);             \
    GLOAD16(bp + (size_t)96  * D_,  &Bs[buf_][lds_off + 96 * BK]);             \
  }

  // ---- swizzled LDS read offsets (elements); read row&7 == lane&7 ----
  const int sw  = (lane & 7) << 3;
  const int aq  = lane >> 4;
  const int ce0 = (aq * 8) ^ sw;
  const int ce1 = (aq * 8 + 32) ^ sw;
  const int arow = (wm * 64 + (lane & 15)) * BK;
  const int brow = (wn * 64 + (lane & 15)) * BK;

  const f32x4 zero4 = {0.f, 0.f, 0.f, 0.f};
  f32x4 acc[4][4], part[4][4];
#pragma unroll
  for (int i = 0; i < 4; ++i)
#pragma unroll
    for (int j = 0; j < 4; ++j) { acc[i][j] = zero4; part[i][j] = zero4; }

  // ---- prologue: stage tile 0 (h=0, k=0) ----
  STAGE_A(0, 0);
  STAGE_B(0, 0);
  asm volatile("s_waitcnt vmcnt(0) lgkmcnt(0)" ::: "memory");
  __builtin_amdgcn_s_barrier();

  for (int t = 0; t < NT; ++t) {
    const u16* Ab = &As[t & 1][0];
    const u16* Bb = &Bs[t & 1][0];

    // ---- all 16 frag reads (kk0 + kk1) ----
    short8 af0[4], bf0[4], af1[4], bf1[4];
#pragma unroll
    for (int fm = 0; fm < 4; ++fm)
      af0[fm] = *(const short8*)&Ab[arow + fm * 16 * BK + ce0];
#pragma unroll
    for (int fn = 0; fn < 4; ++fn)
      bf0[fn] = *(const short8*)&Bb[brow + fn * 16 * BK + ce0];
#pragma unroll
    for (int fm = 0; fm < 4; ++fm)
      af1[fm] = *(const short8*)&Ab[arow + fm * 16 * BK + ce1];
#pragma unroll
    for (int fn = 0; fn < 4; ++fn)
      bf1[fn] = *(const short8*)&Bb[brow + fn * 16 * BK + ce1];

    // ---- stage tile t+1 into slot (t+1)&1 (8 issues) ----
    if (t + 1 < NT) {
      const int t1 = t + 1;
      STAGE_A((t1 & 15), (t1 & 1));                       // k-tile INDEX
      STAGE_B(((size_t)(t1 >> 4) * O_) * D_ + (size_t)((t1 & 15) * 64),
              (t1 & 1));
    }

    // ---- 32 MFMA ----
    __builtin_amdgcn_s_setprio(1);
#pragma unroll
    for (int fm = 0; fm < 4; ++fm)
#pragma unroll
      for (int fn = 0; fn < 4; ++fn)
        part[fm][fn] = __builtin_amdgcn_mfma_f32_16x16x32_bf16(
            af0[fm], bf0[fn], part[fm][fn], 0, 0, 0);
#pragma unroll
    for (int fm = 0; fm < 4; ++fm)
#pragma unroll
      for (int fn = 0; fn < 4; ++fn)
        part[fm][fn] = __builtin_amdgcn_mfma_f32_16x16x32_bf16(
            af1[fm], bf1[fn], part[fm][fn], 0, 0, 0);
    __builtin_amdgcn_s_setprio(0);

    // ---- drain t+1 loads (they had the whole tile to land) + barrier ----
    asm volatile("s_waitcnt vmcnt(0)" ::: "memory");
    __builtin_amdgcn_s_barrier();

    // ============ fold at end of each expert h ============
    if ((t & 15) == 15) {
      const int h = t >> 4;
      float ebv[4];
#pragma unroll
      for (int fn = 0; fn < 4; ++fn)
        ebv[fn] = ebs[h][wn * 64 + fn * 16 + (lane & 15)];
#pragma unroll
      for (int fm = 0; fm < 4; ++fm) {
        const f32x4 gg =
            *(const f32x4*)&gs[h][wm * 64 + fm * 16 + (lane >> 4) * 4];
#pragma unroll
        for (int fn = 0; fn < 4; ++fn)
#pragma unroll
          for (int j = 0; j < 4; ++j) {
            acc[fm][fn][j] += gg[j] * (part[fm][fn][j] + ebv[fn]);
            part[fm][fn][j] = 0.f;
          }
      }
    }
  }

  // ---- epilogue: C/D layout col = lane&15, row = (lane>>4)*4 + j ----
  const int crow = row0 + wm * 64 + (lane >> 4) * 4;
  const int ccol = col0 + wn * 64 + (lane & 15);
#pragma unroll
  for (int fm = 0; fm < 4; ++fm)
#pragma unroll
    for (int fn = 0; fn < 4; ++fn)
#pragma unroll
      for (int j = 0; j < 4; ++j)
        out[(size_t)(crow + fm * 16 + j) * O_ + (ccol + fn * 16)] =
            acc[fm][fn][j];
}

// ---------------------------------------------------------------------------
extern "C" void kernel_launch(void* const* d_in, const int* in_sizes, int n_in,
                              void* d_out, int out_size, void* d_ws,
                              size_t ws_size, hipStream_t stream) {
  const float* x   = (const float*)d_in[0];
  const float* gw  = (const float*)d_in[1];
  const float* gb  = (const float*)d_in[2];
  const float* ew  = (const float*)d_in[3];
  const float* ebp = (const float*)d_in[4];
  float* out = (float*)d_out;

  u16*   x_bf = (u16*)d_ws;                                            // 16 MB
  u16*   w_bf = (u16*)((char*)d_ws + (size_t)BS_ * D_ * 2);            // 16 MB
  float* gbuf = (float*)((char*)d_ws + (size_t)BS_ * D_ * 2 +
                         (size_t)H_ * O_ * D_ * 2);                    // 256 KB

  gate_conv_kernel<<<BS_ / 4, 256, 0, stream>>>(x, gw, gb, x_bf, gbuf);
  convw_kernel<<<(H_ * O_ * D_) / 2048, 256, 0, stream>>>(ew, w_bf);
  moe_gemm_kernel<<<(BS_ / BM) * (O_ / BN), 256, 0, stream>>>(x_bf, w_bf, gbuf,
                                                              ebp, out);
}

// Round 16
// 193.111 us; speedup vs baseline: 1.1838x; 1.1838x over previous
//
#include <hip/hip_runtime.h>
#include <hip/hip_bf16.h>
#include <stdint.h>

#define B_  4
#define S_  2048
#define BS_ (B_ * S_)   // 8192 tokens
#define D_  1024
#define O_  1024
#define H_  8

#define BM 256
#define BN 128
#define BK 64
#define NT 128          // K' tiles: (h,k) combined, 8*1024/64

#define GATE_BLOCKS (BS_ / 4)                 // 2048
#define CONVW_BLOCKS ((H_ * O_ * D_) / 2048)  // 4096

typedef unsigned short u16;
typedef __attribute__((ext_vector_type(8))) short     short8;
typedef __attribute__((ext_vector_type(8))) unsigned short ushort8v;
typedef __attribute__((ext_vector_type(4))) float     f32x4;

__device__ __forceinline__ u16 f2bf(float f) {
  unsigned u = __float_as_uint(f);
  unsigned r = (u + 0x7fffu + ((u >> 16) & 1u)) >> 16;
  return (u16)r;
}

#define GLOAD16(gp, lp)                                                        \
  __builtin_amdgcn_global_load_lds(                                            \
      (const __attribute__((address_space(1))) void*)(gp),                     \
      (__attribute__((address_space(3))) void*)(lp), 16, 0, 0)

// ---------------------------------------------------------------------------
// Kernel 1 (fused preprocess): blocks [0,GATE_BLOCKS): gates (f32, one wave
// per token) + x -> bf16; blocks [GATE_BLOCKS, +CONVW_BLOCKS): expert_w
// f32 -> bf16.  Both roles are HBM-BW-bound; fusing saves a launch gap and
// overlaps the two streams.
// ---------------------------------------------------------------------------
__global__ __launch_bounds__(256) void prep_kernel(
    const float* __restrict__ x, const float* __restrict__ gate_w,
    const float* __restrict__ gate_b, const float* __restrict__ ew,
    u16* __restrict__ x_bf, u16* __restrict__ w_bf,
    float* __restrict__ g_out) {
  if (blockIdx.x < GATE_BLOCKS) {
    // ---- gate + x->bf16 role ----
    const int wave  = threadIdx.x >> 6;
    const int lane  = threadIdx.x & 63;
    const int token = blockIdx.x * 4 + wave;
    const float* xr = x + (size_t)token * D_;
    const int d0 = lane * 16;

    float4 xv[4];
#pragma unroll
    for (int i = 0; i < 4; ++i) xv[i] = *(const float4*)(xr + d0 + i * 4);

    ushort8v lo, hi;
#pragma unroll
    for (int i = 0; i < 2; ++i) {
      lo[i * 4 + 0] = f2bf(xv[i].x); lo[i * 4 + 1] = f2bf(xv[i].y);
      lo[i * 4 + 2] = f2bf(xv[i].z); lo[i * 4 + 3] = f2bf(xv[i].w);
      hi[i * 4 + 0] = f2bf(xv[2 + i].x); hi[i * 4 + 1] = f2bf(xv[2 + i].y);
      hi[i * 4 + 2] = f2bf(xv[2 + i].z); hi[i * 4 + 3] = f2bf(xv[2 + i].w);
    }
    *(ushort8v*)(x_bf + (size_t)token * D_ + d0) = lo;
    *(ushort8v*)(x_bf + (size_t)token * D_ + d0 + 8) = hi;

    float s[H_];
#pragma unroll
    for (int h = 0; h < H_; ++h) {
      const float* gw = gate_w + h * D_ + d0;
      float a = 0.f;
#pragma unroll
      for (int i = 0; i < 4; ++i) {
        float4 w = *(const float4*)(gw + i * 4);
        a += xv[i].x * w.x + xv[i].y * w.y + xv[i].z * w.z + xv[i].w * w.w;
      }
      s[h] = a;
    }
#pragma unroll
    for (int h = 0; h < H_; ++h) {
#pragma unroll
      for (int off = 32; off > 0; off >>= 1) s[h] += __shfl_xor(s[h], off);
      s[h] += gate_b[h];
    }
    float m = s[0];
#pragma unroll
    for (int h = 1; h < H_; ++h) m = fmaxf(m, s[h]);
    float sum = 0.f;
#pragma unroll
    for (int h = 0; h < H_; ++h) { s[h] = expf(s[h] - m); sum += s[h]; }
    const float inv = 1.0f / sum;
#pragma unroll
    for (int h = 0; h < H_; ++h) s[h] *= inv;

    if (lane == 0) {
      float4 g0 = make_float4(s[0], s[1], s[2], s[3]);
      float4 g1 = make_float4(s[4], s[5], s[6], s[7]);
      *(float4*)(g_out + (size_t)token * H_)     = g0;
      *(float4*)(g_out + (size_t)token * H_ + 4) = g1;
    }
  } else {
    // ---- expert_w f32 -> bf16 role ----
    size_t i = (((size_t)(blockIdx.x - GATE_BLOCKS)) * 256 + threadIdx.x) * 8;
    float4 a = *(const float4*)(ew + i);
    float4 b = *(const float4*)(ew + i + 4);
    ushort8v v;
    v[0] = f2bf(a.x); v[1] = f2bf(a.y); v[2] = f2bf(a.z); v[3] = f2bf(a.w);
    v[4] = f2bf(b.x); v[5] = f2bf(b.y); v[6] = f2bf(b.z); v[7] = f2bf(b.w);
    *(ushort8v*)(w_bf + i) = v;
  }
}

// ---------------------------------------------------------------------------
// Kernel 2: fused MoE GEMM == R13 VERBATIM (best verified: GEMM 139us,
// MfmaUtil 43.4, FETCH 99MB, 0 conflicts, VGPR 108, no spill) with ONE
// zero-risk reorder: the 6 prefetch gload issues now come BEFORE the 16
// ds_reads (same count/order relative to the barrier -> vmcnt ledger
// identical; loads gain ~100+ cyc of latency cover under the reads).
// Structure: BM=256 x BN=128, BK=64, 8 waves (4Mx2N, per-wave 64x64),
// grid=256 (1 block/CU), h-outer t=(h,k) walk, 3-deep LDS ring, fused
// single-barrier tile, counted vmcnt(6) (never 0 mid-loop; waits only on
// loads issued a FULL TILE earlier -- R15's 2-deep drain-per-tile variant
// regressed 53%), setprio around MFMA, 3-bit XOR swizzle elem^=(row&7)<<3,
// XCD row-panel-group mapping, per-h fold acc += g_h*(part+eb).
// ---------------------------------------------------------------------------
__global__ __launch_bounds__(512, 2) void moe_gemm_kernel(
    const u16* __restrict__ Xb, const u16* __restrict__ Wb,
    const float* __restrict__ g, const float* __restrict__ eb,
    float* __restrict__ out) {
  __shared__ __align__(16) u16 As[3][BM * BK];   // 3 x 32 KB
  __shared__ __align__(16) u16 Bs[3][BN * BK];   // 3 x 16 KB
  __shared__ float gs[H_][BM];                   // 8 KB, transposed
  __shared__ float ebs[H_][BN];                  // 4 KB

  const int tid  = threadIdx.x;
  const int wave = tid >> 6;
  const int lane = tid & 63;

  // ---- XCD-affine mapping: xcd = bx&7 owns row panels 4*(bx&7)+(bx>>6) ----
  const int bx   = blockIdx.x;                 // 256 blocks
  const int row0 = ((bx & 7) * 4 + (bx >> 6)) * BM;   // 32 row panels
  const int col0 = ((bx >> 3) & 7) * BN;               // 8 col panels

  for (int i = tid; i < H_ * BM; i += 512) {
    int h = i >> 8, r = i & 255;
    gs[h][r] = g[(size_t)(row0 + r) * H_ + h];
  }
  for (int i = tid; i < H_ * BN; i += 512) {
    int h = i >> 7, c = i & 127;
    ebs[h][c] = eb[h * O_ + col0 + c];
  }

  const int wm = wave >> 1;  // 0..3 : 64-row band
  const int wn = wave & 1;   // 0..1 : 64-col band

  // ---- staging source (inverse-swizzled global addr; LDS dest linear) ----
  const int s_row = wave * 8 + (lane >> 3);               // row in 64-group
  const int s_col = ((lane & 7) * 8) ^ (((lane >> 3) & 7) << 3);
  const u16* a_base = Xb + (size_t)(row0 + s_row) * D_ + s_col;
  const u16* b_base = Wb + (size_t)(col0 + s_row) * D_ + s_col;
  const int lds_off = (wave * 8) * BK;                    // elems, wave-uniform

  // ---- swizzled LDS read offsets (elements); read row&7 == lane&7 ----
  const int sw  = (lane & 7) << 3;
  const int aq  = lane >> 4;
  const int ce0 = (aq * 8) ^ sw;
  const int ce1 = (aq * 8 + 32) ^ sw;
  const int arow = (wm * 64 + (lane & 15)) * BK;
  const int brow = (wn * 64 + (lane & 15)) * BK;

  const f32x4 zero4 = {0.f, 0.f, 0.f, 0.f};
  f32x4 acc[4][4], part[4][4];
#pragma unroll
  for (int i = 0; i < 4; ++i)
#pragma unroll
    for (int j = 0; j < 4; ++j) { acc[i][j] = zero4; part[i][j] = zero4; }

  // ---- prologue: stage tiles 0 and 1 (both h=0) ----
#pragma unroll
  for (int i = 0; i < 4; ++i)
    GLOAD16(a_base + (size_t)(i * 64) * D_, &As[0][lds_off + i * 64 * BK]);
#pragma unroll
  for (int j = 0; j < 2; ++j)
    GLOAD16(b_base + (size_t)(j * 64) * D_, &Bs[0][lds_off + j * 64 * BK]);
#pragma unroll
  for (int i = 0; i < 4; ++i)
    GLOAD16(a_base + (size_t)(i * 64) * D_ + 64, &As[1][lds_off + i * 64 * BK]);
#pragma unroll
  for (int j = 0; j < 2; ++j)
    GLOAD16(b_base + (size_t)(j * 64) * D_ + 64, &Bs[1][lds_off + j * 64 * BK]);

  asm volatile("s_waitcnt vmcnt(6) lgkmcnt(0)" ::: "memory");
  __builtin_amdgcn_s_barrier();

  int buf = 0;
  for (int t = 0; t < NT; ++t) {
    const u16* Ab = &As[buf][0];
    const u16* Bb = &Bs[buf][0];
    const int t2 = t + 2;
    const int sbuf = (buf + 2 >= 3) ? buf - 1 : buf + 2;

    // ---- prefetch tile t+2 FIRST (6 issues; max latency cover) ----
    if (t2 < NT) {
      const size_t koff = (size_t)((t2 & 15) * 64);
#pragma unroll
      for (int i = 0; i < 4; ++i)
        GLOAD16(a_base + (size_t)(i * 64) * D_ + koff,
                &As[sbuf][lds_off + i * 64 * BK]);
      const size_t boff = ((size_t)(t2 >> 4) * O_) * D_ + koff;
#pragma unroll
      for (int j = 0; j < 2; ++j)
        GLOAD16(b_base + (size_t)(j * 64) * D_ + boff,
                &Bs[sbuf][lds_off + j * 64 * BK]);
    }

    // ---- all 16 frag reads (kk0 + kk1) ----
    short8 af0[4], bf0[4], af1[4], bf1[4];
#pragma unroll
    for (int fm = 0; fm < 4; ++fm)
      af0[fm] = *(const short8*)&Ab[arow + fm * 16 * BK + ce0];
#pragma unroll
    for (int fn = 0; fn < 4; ++fn)
      bf0[fn] = *(const short8*)&Bb[brow + fn * 16 * BK + ce0];
#pragma unroll
    for (int fm = 0; fm < 4; ++fm)
      af1[fm] = *(const short8*)&Ab[arow + fm * 16 * BK + ce1];
#pragma unroll
    for (int fn = 0; fn < 4; ++fn)
      bf1[fn] = *(const short8*)&Bb[brow + fn * 16 * BK + ce1];

    // ---- 32 MFMA (compiler interleaves lgkmcnt waits with frag arrival) ----
    __builtin_amdgcn_s_setprio(1);
#pragma unroll
    for (int fm = 0; fm < 4; ++fm)
#pragma unroll
      for (int fn = 0; fn < 4; ++fn)
        part[fm][fn] = __builtin_amdgcn_mfma_f32_16x16x32_bf16(
            af0[fm], bf0[fn], part[fm][fn], 0, 0, 0);
#pragma unroll
    for (int fm = 0; fm < 4; ++fm)
#pragma unroll
      for (int fn = 0; fn < 4; ++fn)
        part[fm][fn] = __builtin_amdgcn_mfma_f32_16x16x32_bf16(
            af1[fm], bf1[fn], part[fm][fn], 0, 0, 0);
    __builtin_amdgcn_s_setprio(0);

    // ---- one counted-vmcnt + one barrier per tile ----
    if (t < NT - 2) {
      asm volatile("s_waitcnt vmcnt(6)" ::: "memory");  // t+1 ready, t+2 in flight
    } else {
      asm volatile("s_waitcnt vmcnt(0)" ::: "memory");
    }
    __builtin_amdgcn_s_barrier();

    // ============ fold at end of each expert h ============
    if ((t & 15) == 15) {
      const int h = t >> 4;
      float ebv[4];
#pragma unroll
      for (int fn = 0; fn < 4; ++fn)
        ebv[fn] = ebs[h][wn * 64 + fn * 16 + (lane & 15)];
#pragma unroll
      for (int fm = 0; fm < 4; ++fm) {
        const f32x4 gg =
            *(const f32x4*)&gs[h][wm * 64 + fm * 16 + (lane >> 4) * 4];
#pragma unroll
        for (int fn = 0; fn < 4; ++fn)
#pragma unroll
          for (int j = 0; j < 4; ++j) {
            acc[fm][fn][j] += gg[j] * (part[fm][fn][j] + ebv[fn]);
            part[fm][fn][j] = 0.f;
          }
      }
    }

    buf = (buf == 2) ? 0 : buf + 1;
  }

  // ---- epilogue: C/D layout col = lane&15, row = (lane>>4)*4 + j ----
  const int crow = row0 + wm * 64 + (lane >> 4) * 4;
  const int ccol = col0 + wn * 64 + (lane & 15);
#pragma unroll
  for (int fm = 0; fm < 4; ++fm)
#pragma unroll
    for (int fn = 0; fn < 4; ++fn)
#pragma unroll
      for (int j = 0; j < 4; ++j)
        out[(size_t)(crow + fm * 16 + j) * O_ + (ccol + fn * 16)] =
            acc[fm][fn][j];
}

// ---------------------------------------------------------------------------
extern "C" void kernel_launch(void* const* d_in, const int* in_sizes, int n_in,
                              void* d_out, int out_size, void* d_ws,
                              size_t ws_size, hipStream_t stream) {
  const float* x   = (const float*)d_in[0];
  const float* gw  = (const float*)d_in[1];
  const float* gb  = (const float*)d_in[2];
  const float* ew  = (const float*)d_in[3];
  const float* ebp = (const float*)d_in[4];
  float* out = (float*)d_out;

  u16*   x_bf = (u16*)d_ws;                                            // 16 MB
  u16*   w_bf = (u16*)((char*)d_ws + (size_t)BS_ * D_ * 2);            // 16 MB
  float* gbuf = (float*)((char*)d_ws + (size_t)BS_ * D_ * 2 +
                         (size_t)H_ * O_ * D_ * 2);                    // 256 KB

  prep_kernel<<<GATE_BLOCKS + CONVW_BLOCKS, 256, 0, stream>>>(
      x, gw, gb, ew, x_bf, w_bf, gbuf);
  moe_gemm_kernel<<<(BS_ / BM) * (O_ / BN), 512, 0, stream>>>(x_bf, w_bf, gbuf,
                                                              ebp, out);
}

// Round 17
// 154.053 us; speedup vs baseline: 1.4839x; 1.2535x over previous
//
#include <hip/hip_runtime.h>
#include <hip/hip_bf16.h>
#include <stdint.h>

#define B_  4
#define S_  2048
#define BS_ (B_ * S_)   // 8192 tokens
#define D_  1024
#define O_  1024
#define H_  8

#define BM 256
#define BN 128
#define BK 64
#define NT 128          // K' tiles: (h,k) combined, 8*1024/64

#define GATE_BLOCKS (BS_ / 4)                 // 2048
#define CONVW_BLOCKS ((H_ * O_ * D_) / 2048)  // 4096

typedef unsigned short u16;
typedef __attribute__((ext_vector_type(8))) short     short8;
typedef __attribute__((ext_vector_type(8))) unsigned short ushort8v;
typedef __attribute__((ext_vector_type(4))) float     f32x4;

__device__ __forceinline__ u16 f2bf(float f) {
  unsigned u = __float_as_uint(f);
  unsigned r = (u + 0x7fffu + ((u >> 16) & 1u)) >> 16;
  return (u16)r;
}

#define GLOAD16(gp, lp)                                                        \
  __builtin_amdgcn_global_load_lds(                                            \
      (const __attribute__((address_space(1))) void*)(gp),                     \
      (__attribute__((address_space(3))) void*)(lp), 16, 0, 0)

// ---------------------------------------------------------------------------
// Kernel 1 (fused preprocess; VERIFIED R16: ~9.5us vs 19us for two
// launches): blocks [0,GATE_BLOCKS): gates (f32, one wave per token) +
// x -> bf16; blocks [GATE_BLOCKS, +CONVW_BLOCKS): expert_w f32 -> bf16.
// ---------------------------------------------------------------------------
__global__ __launch_bounds__(256) void prep_kernel(
    const float* __restrict__ x, const float* __restrict__ gate_w,
    const float* __restrict__ gate_b, const float* __restrict__ ew,
    u16* __restrict__ x_bf, u16* __restrict__ w_bf,
    float* __restrict__ g_out) {
  if (blockIdx.x < GATE_BLOCKS) {
    // ---- gate + x->bf16 role ----
    const int wave  = threadIdx.x >> 6;
    const int lane  = threadIdx.x & 63;
    const int token = blockIdx.x * 4 + wave;
    const float* xr = x + (size_t)token * D_;
    const int d0 = lane * 16;

    float4 xv[4];
#pragma unroll
    for (int i = 0; i < 4; ++i) xv[i] = *(const float4*)(xr + d0 + i * 4);

    ushort8v lo, hi;
#pragma unroll
    for (int i = 0; i < 2; ++i) {
      lo[i * 4 + 0] = f2bf(xv[i].x); lo[i * 4 + 1] = f2bf(xv[i].y);
      lo[i * 4 + 2] = f2bf(xv[i].z); lo[i * 4 + 3] = f2bf(xv[i].w);
      hi[i * 4 + 0] = f2bf(xv[2 + i].x); hi[i * 4 + 1] = f2bf(xv[2 + i].y);
      hi[i * 4 + 2] = f2bf(xv[2 + i].z); hi[i * 4 + 3] = f2bf(xv[2 + i].w);
    }
    *(ushort8v*)(x_bf + (size_t)token * D_ + d0) = lo;
    *(ushort8v*)(x_bf + (size_t)token * D_ + d0 + 8) = hi;

    float s[H_];
#pragma unroll
    for (int h = 0; h < H_; ++h) {
      const float* gw = gate_w + h * D_ + d0;
      float a = 0.f;
#pragma unroll
      for (int i = 0; i < 4; ++i) {
        float4 w = *(const float4*)(gw + i * 4);
        a += xv[i].x * w.x + xv[i].y * w.y + xv[i].z * w.z + xv[i].w * w.w;
      }
      s[h] = a;
    }
#pragma unroll
    for (int h = 0; h < H_; ++h) {
#pragma unroll
      for (int off = 32; off > 0; off >>= 1) s[h] += __shfl_xor(s[h], off);
      s[h] += gate_b[h];
    }
    float m = s[0];
#pragma unroll
    for (int h = 1; h < H_; ++h) m = fmaxf(m, s[h]);
    float sum = 0.f;
#pragma unroll
    for (int h = 0; h < H_; ++h) { s[h] = expf(s[h] - m); sum += s[h]; }
    const float inv = 1.0f / sum;
#pragma unroll
    for (int h = 0; h < H_; ++h) s[h] *= inv;

    if (lane == 0) {
      float4 g0 = make_float4(s[0], s[1], s[2], s[3]);
      float4 g1 = make_float4(s[4], s[5], s[6], s[7]);
      *(float4*)(g_out + (size_t)token * H_)     = g0;
      *(float4*)(g_out + (size_t)token * H_ + 4) = g1;
    }
  } else {
    // ---- expert_w f32 -> bf16 role ----
    size_t i = (((size_t)(blockIdx.x - GATE_BLOCKS)) * 256 + threadIdx.x) * 8;
    float4 a = *(const float4*)(ew + i);
    float4 b = *(const float4*)(ew + i + 4);
    ushort8v v;
    v[0] = f2bf(a.x); v[1] = f2bf(a.y); v[2] = f2bf(a.z); v[3] = f2bf(a.w);
    v[4] = f2bf(b.x); v[5] = f2bf(b.y); v[6] = f2bf(b.z); v[7] = f2bf(b.w);
    *(ushort8v*)(w_bf + i) = v;
  }
}

// ---------------------------------------------------------------------------
// Kernel 2: fused MoE GEMM == R13 BYTE-EXACT (best verified: GEMM 139us,
// MfmaUtil 43.4, FETCH 99MB, 0 conflicts, VGPR 108, no spill).
// R16 lesson: moving the 6 prefetch gload issues BEFORE the ds_reads cost
// 44us (139->183, MfmaUtil 43->31) -- the gload issue+addr chains delayed
// the critical-path frag loads while gaining nothing (gloads already had a
// full-tile slack in the 3-deep ring).  Order restored: ds_reads FIRST,
// then prefetch issues, then MFMA.
// Structure: BM=256 x BN=128, BK=64, 8 waves (4Mx2N, per-wave 64x64),
// grid=256 (1 block/CU), h-outer t=(h,k) walk, 3-deep LDS ring, fused
// single-barrier tile, counted vmcnt(6) (never 0 mid-loop; waits only on
// loads issued a FULL TILE earlier -- R15's 2-deep drain-per-tile variant
// regressed 53%), setprio around MFMA, 3-bit XOR swizzle elem^=(row&7)<<3,
// XCD row-panel-group mapping, per-h fold acc += g_h*(part+eb).
// ---------------------------------------------------------------------------
__global__ __launch_bounds__(512, 2) void moe_gemm_kernel(
    const u16* __restrict__ Xb, const u16* __restrict__ Wb,
    const float* __restrict__ g, const float* __restrict__ eb,
    float* __restrict__ out) {
  __shared__ __align__(16) u16 As[3][BM * BK];   // 3 x 32 KB
  __shared__ __align__(16) u16 Bs[3][BN * BK];   // 3 x 16 KB
  __shared__ float gs[H_][BM];                   // 8 KB, transposed
  __shared__ float ebs[H_][BN];                  // 4 KB

  const int tid  = threadIdx.x;
  const int wave = tid >> 6;
  const int lane = tid & 63;

  // ---- XCD-affine mapping: xcd = bx&7 owns row panels 4*(bx&7)+(bx>>6) ----
  const int bx   = blockIdx.x;                 // 256 blocks
  const int row0 = ((bx & 7) * 4 + (bx >> 6)) * BM;   // 32 row panels
  const int col0 = ((bx >> 3) & 7) * BN;               // 8 col panels

  for (int i = tid; i < H_ * BM; i += 512) {
    int h = i >> 8, r = i & 255;
    gs[h][r] = g[(size_t)(row0 + r) * H_ + h];
  }
  for (int i = tid; i < H_ * BN; i += 512) {
    int h = i >> 7, c = i & 127;
    ebs[h][c] = eb[h * O_ + col0 + c];
  }

  const int wm = wave >> 1;  // 0..3 : 64-row band
  const int wn = wave & 1;   // 0..1 : 64-col band

  // ---- staging source (inverse-swizzled global addr; LDS dest linear) ----
  const int s_row = wave * 8 + (lane >> 3);               // row in 64-group
  const int s_col = ((lane & 7) * 8) ^ (((lane >> 3) & 7) << 3);
  const u16* a_base = Xb + (size_t)(row0 + s_row) * D_ + s_col;
  const u16* b_base = Wb + (size_t)(col0 + s_row) * D_ + s_col;
  const int lds_off = (wave * 8) * BK;                    // elems, wave-uniform

  // ---- swizzled LDS read offsets (elements); read row&7 == lane&7 ----
  const int sw  = (lane & 7) << 3;
  const int aq  = lane >> 4;
  const int ce0 = (aq * 8) ^ sw;
  const int ce1 = (aq * 8 + 32) ^ sw;
  const int arow = (wm * 64 + (lane & 15)) * BK;
  const int brow = (wn * 64 + (lane & 15)) * BK;

  const f32x4 zero4 = {0.f, 0.f, 0.f, 0.f};
  f32x4 acc[4][4], part[4][4];
#pragma unroll
  for (int i = 0; i < 4; ++i)
#pragma unroll
    for (int j = 0; j < 4; ++j) { acc[i][j] = zero4; part[i][j] = zero4; }

  // ---- prologue: stage tiles 0 and 1 (both h=0) ----
#pragma unroll
  for (int i = 0; i < 4; ++i)
    GLOAD16(a_base + (size_t)(i * 64) * D_, &As[0][lds_off + i * 64 * BK]);
#pragma unroll
  for (int j = 0; j < 2; ++j)
    GLOAD16(b_base + (size_t)(j * 64) * D_, &Bs[0][lds_off + j * 64 * BK]);
#pragma unroll
  for (int i = 0; i < 4; ++i)
    GLOAD16(a_base + (size_t)(i * 64) * D_ + 64, &As[1][lds_off + i * 64 * BK]);
#pragma unroll
  for (int j = 0; j < 2; ++j)
    GLOAD16(b_base + (size_t)(j * 64) * D_ + 64, &Bs[1][lds_off + j * 64 * BK]);

  asm volatile("s_waitcnt vmcnt(6) lgkmcnt(0)" ::: "memory");
  __builtin_amdgcn_s_barrier();

  int buf = 0;
  for (int t = 0; t < NT; ++t) {
    const u16* Ab = &As[buf][0];
    const u16* Bb = &Bs[buf][0];
    const int t2 = t + 2;
    const int sbuf = (buf + 2 >= 3) ? buf - 1 : buf + 2;

    // ---- all 16 frag reads (kk0 + kk1) FIRST (critical path) ----
    short8 af0[4], bf0[4], af1[4], bf1[4];
#pragma unroll
    for (int fm = 0; fm < 4; ++fm)
      af0[fm] = *(const short8*)&Ab[arow + fm * 16 * BK + ce0];
#pragma unroll
    for (int fn = 0; fn < 4; ++fn)
      bf0[fn] = *(const short8*)&Bb[brow + fn * 16 * BK + ce0];
#pragma unroll
    for (int fm = 0; fm < 4; ++fm)
      af1[fm] = *(const short8*)&Ab[arow + fm * 16 * BK + ce1];
#pragma unroll
    for (int fn = 0; fn < 4; ++fn)
      bf1[fn] = *(const short8*)&Bb[brow + fn * 16 * BK + ce1];

    // ---- prefetch tile t+2 (6 issues; has full-tile slack) ----
    if (t2 < NT) {
      const size_t koff = (size_t)((t2 & 15) * 64);
#pragma unroll
      for (int i = 0; i < 4; ++i)
        GLOAD16(a_base + (size_t)(i * 64) * D_ + koff,
                &As[sbuf][lds_off + i * 64 * BK]);
      const size_t boff = ((size_t)(t2 >> 4) * O_) * D_ + koff;
#pragma unroll
      for (int j = 0; j < 2; ++j)
        GLOAD16(b_base + (size_t)(j * 64) * D_ + boff,
                &Bs[sbuf][lds_off + j * 64 * BK]);
    }

    // ---- 32 MFMA (compiler interleaves lgkmcnt waits with frag arrival) ----
    __builtin_amdgcn_s_setprio(1);
#pragma unroll
    for (int fm = 0; fm < 4; ++fm)
#pragma unroll
      for (int fn = 0; fn < 4; ++fn)
        part[fm][fn] = __builtin_amdgcn_mfma_f32_16x16x32_bf16(
            af0[fm], bf0[fn], part[fm][fn], 0, 0, 0);
#pragma unroll
    for (int fm = 0; fm < 4; ++fm)
#pragma unroll
      for (int fn = 0; fn < 4; ++fn)
        part[fm][fn] = __builtin_amdgcn_mfma_f32_16x16x32_bf16(
            af1[fm], bf1[fn], part[fm][fn], 0, 0, 0);
    __builtin_amdgcn_s_setprio(0);

    // ---- one counted-vmcnt + one barrier per tile ----
    if (t < NT - 2) {
      asm volatile("s_waitcnt vmcnt(6)" ::: "memory");  // t+1 ready, t+2 in flight
    } else {
      asm volatile("s_waitcnt vmcnt(0)" ::: "memory");
    }
    __builtin_amdgcn_s_barrier();

    // ============ fold at end of each expert h ============
    if ((t & 15) == 15) {
      const int h = t >> 4;
      float ebv[4];
#pragma unroll
      for (int fn = 0; fn < 4; ++fn)
        ebv[fn] = ebs[h][wn * 64 + fn * 16 + (lane & 15)];
#pragma unroll
      for (int fm = 0; fm < 4; ++fm) {
        const f32x4 gg =
            *(const f32x4*)&gs[h][wm * 64 + fm * 16 + (lane >> 4) * 4];
#pragma unroll
        for (int fn = 0; fn < 4; ++fn)
#pragma unroll
          for (int j = 0; j < 4; ++j) {
            acc[fm][fn][j] += gg[j] * (part[fm][fn][j] + ebv[fn]);
            part[fm][fn][j] = 0.f;
          }
      }
    }

    buf = (buf == 2) ? 0 : buf + 1;
  }

  // ---- epilogue: C/D layout col = lane&15, row = (lane>>4)*4 + j ----
  const int crow = row0 + wm * 64 + (lane >> 4) * 4;
  const int ccol = col0 + wn * 64 + (lane & 15);
#pragma unroll
  for (int fm = 0; fm < 4; ++fm)
#pragma unroll
    for (int fn = 0; fn < 4; ++fn)
#pragma unroll
      for (int j = 0; j < 4; ++j)
        out[(size_t)(crow + fm * 16 + j) * O_ + (ccol + fn * 16)] =
            acc[fm][fn][j];
}

// ---------------------------------------------------------------------------
extern "C" void kernel_launch(void* const* d_in, const int* in_sizes, int n_in,
                              void* d_out, int out_size, void* d_ws,
                              size_t ws_size, hipStream_t stream) {
  const float* x   = (const float*)d_in[0];
  const float* gw  = (const float*)d_in[1];
  const float* gb  = (const float*)d_in[2];
  const float* ew  = (const float*)d_in[3];
  const float* ebp = (const float*)d_in[4];
  float* out = (float*)d_out;

  u16*   x_bf = (u16*)d_ws;                                            // 16 MB
  u16*   w_bf = (u16*)((char*)d_ws + (size_t)BS_ * D_ * 2);            // 16 MB
  float* gbuf = (float*)((char*)d_ws + (size_t)BS_ * D_ * 2 +
                         (size_t)H_ * O_ * D_ * 2);                    // 256 KB

  prep_kernel<<<GATE_BLOCKS + CONVW_BLOCKS, 256, 0, stream>>>(
      x, gw, gb, ew, x_bf, w_bf, gbuf);
  moe_gemm_kernel<<<(BS_ / BM) * (O_ / BN), 512, 0, stream>>>(x_bf, w_bf, gbuf,
                                                              ebp, out);
}